// Round 2
// baseline (156.383 us; speedup 1.0000x reference)
//
#include <hip/hip_runtime.h>
#include <math.h>

// GeometricAttentionClassifier: B=8, N=512, F=16, D=20, Fv=1.
// alpha depends only on pairwise distance d -> tabulate scalar g(d):
//   g(d)  = sum_f w_a[f] * tanh(sum_k exp(-10*(d-0.1k)^2) * W_e[k,f] + b_e[f])
//   alpha = g(d) - g(0); v1[b,m] = a*(1 + S[b,m]/N - g0), S = row sums of g;
//   out[b] = (v1[b,0] + (1/N) sum_m (g(d_{0,m})-g0) v1[b,m]) * Wq + bq
//
// R1: 3 kernels -> 2. rows+finalize fused via last-block ticket (threadfence +
// device-scope atomicAdd). LUT 4096 -> 2048 entries (lerp err ~1e-5 << 4e-2 thr).

#define BB 8
#define NN 512
#define FF 16
#define DD 20
#define TBL 2048
#define DMAX 1.7320509f  // sqrt(3): coords uniform in [0,1)

// ws float layout: [0] ticket counter (int), [16 .. 16+TBL] table, [TBL+32 ...] Srow
#define WS_TBL_OFF 16
#define WS_SROW_OFF (WS_TBL_OFF + TBL + 16)

__device__ __forceinline__ float eval_g(float d, const float* __restrict__ We,
                                        const float* __restrict__ be,
                                        const float* __restrict__ wa) {
    float z[FF];
#pragma unroll
    for (int f = 0; f < FF; ++f) z[f] = be[f];
#pragma unroll
    for (int k = 0; k < DD; ++k) {
        float u = d - 0.1f * (float)k;
        float r = __expf(-10.0f * u * u);
#pragma unroll
        for (int f = 0; f < FF; ++f) z[f] = fmaf(r, We[k * FF + f], z[f]);
    }
    float g = 0.0f;
#pragma unroll
    for (int f = 0; f < FF; ++f) g += wa[f] * tanhf(z[f]);
    return g;
}

// Kernel 1: build LUT (TBL+1 entries, entry TBL is the lerp pad) + zero ticket.
__global__ void build_table(const float* __restrict__ We, const float* __restrict__ be,
                            const float* __restrict__ wa, float* __restrict__ ws) {
    int i = blockIdx.x * blockDim.x + threadIdx.x;
    if (i == 0) ((int*)ws)[0] = 0;          // ticket for last-block detection
    if (i <= TBL) {
        float d = (DMAX / (float)(TBL - 1)) * (float)i;
        ws[WS_TBL_OFF + i] = eval_g(d, We, be, wa);
    }
}

// Kernel 2: S[b,n] = sum_m g(d_{n,m}) (one wave per row, LUT in LDS), then the
// last block to finish does the finalize (it already holds the LUT in LDS).
__global__ __launch_bounds__(256) void rows_finalize(const float* __restrict__ coords,
                                                     float* __restrict__ ws,
                                                     const float* __restrict__ atom_emb,
                                                     const float* __restrict__ Wq,
                                                     const float* __restrict__ bq,
                                                     float* __restrict__ out) {
    __shared__ float sh[TBL + 1];
    __shared__ float red[BB * 4];
    __shared__ int is_last;
    const float* tbl = ws + WS_TBL_OFF;
    float* Srow = ws + WS_SROW_OFF;
    int* cnt = (int*)ws;

    const int tid = threadIdx.x;
    for (int i = tid; i <= TBL; i += 256) sh[i] = tbl[i];
    __syncthreads();

    const int wave = tid >> 6;
    const int lane = tid & 63;
    const int row  = blockIdx.x * 4 + wave;   // 0..4095
    const int b = row >> 9;
    const int n = row & 511;
    const float* cb = coords + (size_t)b * NN * 3;
    const float cx = cb[n * 3 + 0], cy = cb[n * 3 + 1], cz = cb[n * 3 + 2];
    const float inv_h = (float)(TBL - 1) / DMAX;

    float acc = 0.0f;
    for (int m = lane; m < NN; m += 64) {
        float dx = cx - cb[m * 3 + 0];
        float dy = cy - cb[m * 3 + 1];
        float dz = cz - cb[m * 3 + 2];
        float dd = fmaf(dx, dx, fmaf(dy, dy, dz * dz)) + 1e-12f;
        float x  = sqrtf(dd) * inv_h;
        int  i0  = (int)x;
        i0 = (i0 < TBL - 1) ? i0 : (TBL - 1);
        float fr = x - (float)i0;
        float t0 = sh[i0], t1 = sh[i0 + 1];
        acc += fmaf(fr, t1 - t0, t0);
    }
#pragma unroll
    for (int off = 32; off > 0; off >>= 1) acc += __shfl_down(acc, off, 64);
    if (lane == 0) Srow[row] = acc;

    // --- last-block ticket (rocPRIM-style): release writes, grab ticket ---
    __threadfence();
    __syncthreads();
    if (tid == 0) is_last = (atomicAdd(cnt, 1) == (int)gridDim.x - 1);
    __syncthreads();
    if (!is_last) return;
    __threadfence();  // acquire: make all blocks' Srow visible

    // --- finalize: 8 batches, 512 m each over 256 threads ---
    volatile const float* S = Srow;
    const float g0 = sh[0];
    const float a  = atom_emb[0];
    const float invN = 1.0f / (float)NN;

    float accs[BB];
#pragma unroll
    for (int b2 = 0; b2 < BB; ++b2) accs[b2] = 0.0f;

    for (int b2 = 0; b2 < BB; ++b2) {
        const float* c2 = coords + (size_t)b2 * NN * 3;
        const float ox = c2[0], oy = c2[1], oz = c2[2];
        for (int m = tid; m < NN; m += 256) {
            float dx = ox - c2[m * 3 + 0];
            float dy = oy - c2[m * 3 + 1];
            float dz = oz - c2[m * 3 + 2];
            float dd = fmaf(dx, dx, fmaf(dy, dy, dz * dz)) + 1e-12f;
            float x  = sqrtf(dd) * inv_h;
            int  i0  = (int)x;
            i0 = (i0 < TBL - 1) ? i0 : (TBL - 1);
            float fr = x - (float)i0;
            float al = fmaf(fr, sh[i0 + 1] - sh[i0], sh[i0]) - g0;
            float v1 = a * (1.0f + S[b2 * NN + m] * invN - g0);
            accs[b2] = fmaf(al, v1, accs[b2]);
        }
    }
#pragma unroll
    for (int b2 = 0; b2 < BB; ++b2) {
        float v = accs[b2];
#pragma unroll
        for (int off = 32; off > 0; off >>= 1) v += __shfl_down(v, off, 64);
        if (lane == 0) red[b2 * 4 + wave] = v;
    }
    __syncthreads();
    if (tid < BB) {
        float s = red[tid * 4 + 0] + red[tid * 4 + 1] + red[tid * 4 + 2] + red[tid * 4 + 3];
        float v1_0 = a * (1.0f + S[tid * NN + 0] * invN - g0);
        out[tid] = (v1_0 + s * invN) * Wq[0] + bq[0];
    }
}

extern "C" void kernel_launch(void* const* d_in, const int* in_sizes, int n_in,
                              void* d_out, int out_size, void* d_ws, size_t ws_size,
                              hipStream_t stream) {
    const float* coords   = (const float*)d_in[0];  // (8,512,3)
    const float* atom_emb = (const float*)d_in[1];  // (1,1,1)
    const float* W_e      = (const float*)d_in[2];  // (20,16)
    const float* b_e      = (const float*)d_in[3];  // (16,)
    const float* w_a      = (const float*)d_in[4];  // (16,)
    const float* Wq       = (const float*)d_in[5];  // (1,1)
    const float* bq       = (const float*)d_in[6];  // (1,)
    float* out = (float*)d_out;                     // (8,1)
    float* ws  = (float*)d_ws;

    build_table<<<(TBL + 1 + 255) / 256, 256, 0, stream>>>(W_e, b_e, w_a, ws);
    rows_finalize<<<(BB * NN) / 4, 256, 0, stream>>>(coords, ws, atom_emb, Wq, bq, out);
}

// Round 3
// 139.752 us; speedup vs baseline: 1.1190x; 1.1190x over previous
//
#include <hip/hip_runtime.h>
#include <math.h>

// GeometricAttentionClassifier: B=8, N=512, F=16, D=20, Fv=1.
// alpha depends only on pairwise distance d -> scalar g(d), tabulated in-LDS:
//   g(d) = sum_f w_a[f]*tanh(sum_k exp(-10(d-0.1k)^2) W_e[k,f] + b_e[f]); g0=g(0)
// Order-2 stream collapses (a = atom_emb scalar):
//   S[b,m]  = sum_k g(d_{mk});  v1[b,m] = a(1 + S[b,m]/N - g0)
//   out[b]  = (v1[b,0] + (1/N)(a(1-g0)P1 + (a/N)P2)) * Wq + bq
//   P1 = sum_m alpha_{0m},  P2 = sum_m alpha_{0m} S[b,m]   (alpha_{0m}=g(d_{0m})-g0)
// R2 lesson: last-block ticket = 1024 serialized cross-XCD atomics (83us @ 2.7%
// VALUBusy). R3: partials are block-local -> ZERO atomics, 2 tiny kernels.

#define BB 8
#define NN 512
#define FF 16
#define DD 20
#define TBL 2048            // entries 0..2047; i0<=2046 so no pad entry needed
#define DMAX 1.7320509f     // sqrt(3): coords uniform in [0,1)

// ws float layout: [blk*2 .. +1] = (P1,P2) per block (64 blocks); [128+b] = S0
#define WS_S0_OFF 128

__device__ __forceinline__ float eval_g(float d, const float* __restrict__ We,
                                        const float* __restrict__ be,
                                        const float* __restrict__ wa) {
    float z[FF];
#pragma unroll
    for (int f = 0; f < FF; ++f) z[f] = be[f];
#pragma unroll
    for (int k = 0; k < DD; ++k) {
        float u = d - 0.1f * (float)k;
        float r = __expf(-10.0f * u * u);
#pragma unroll
        for (int f = 0; f < FF; ++f) z[f] = fmaf(r, We[k * FF + f], z[f]);
    }
    float g = 0.0f;
#pragma unroll
    for (int f = 0; f < FF; ++f) g += wa[f] * tanhf(z[f]);
    return g;
}

// K1: 64 blocks x 1024 thr. Block j: batch b=j/8, rows n in [(j%8)*64, +64).
// Builds LUT in-LDS (2 evals/thread), stages coords SoA, computes row sums and
// block-local P1/P2 partials. No global table, no atomics, no fences.
__global__ __launch_bounds__(1024) void rows_partial(const float* __restrict__ coords,
                                                     const float* __restrict__ We,
                                                     const float* __restrict__ be,
                                                     const float* __restrict__ wa,
                                                     float* __restrict__ ws) {
    __shared__ float sh[TBL];
    __shared__ float shx[NN], shy[NN], shz[NN];
    __shared__ float wp1[16], wp2[16];
    __shared__ float s0sh;

    const int tid  = threadIdx.x;
    const int b    = blockIdx.x >> 3;
    const int blk8 = blockIdx.x & 7;
    const float* cb = coords + (size_t)b * NN * 3;

    // stage coords (SoA: lane m -> bank m%32, 2-way aliasing = free)
    if (tid < NN) {
        shx[tid] = cb[tid * 3 + 0];
        shy[tid] = cb[tid * 3 + 1];
        shz[tid] = cb[tid * 3 + 2];
    }
    // build LUT in-LDS: entries tid and tid+1024
    {
        const float h = DMAX / (float)(TBL - 1);
        sh[tid]        = eval_g(h * (float)tid, We, be, wa);
        sh[tid + 1024] = eval_g(h * (float)(tid + 1024), We, be, wa);
    }
    __syncthreads();

    const int wave = tid >> 6;
    const int lane = tid & 63;
    const float inv_h = (float)(TBL - 1) / DMAX;
    const float g0 = sh[0];

    float p1 = 0.0f, p2 = 0.0f;
#pragma unroll
    for (int r = 0; r < 4; ++r) {
        const int n = blk8 * 64 + wave * 4 + r;
        const float cx = shx[n], cy = shy[n], cz = shz[n];
        float acc = 0.0f;
#pragma unroll
        for (int it = 0; it < 8; ++it) {
            const int m = lane + it * 64;
            float dx = cx - shx[m];
            float dy = cy - shy[m];
            float dz = cz - shz[m];
            float dd = fmaf(dx, dx, fmaf(dy, dy, dz * dz)) + 1e-12f;
            float x  = sqrtf(dd) * inv_h;
            int  i0  = (int)x;
            i0 = (i0 < TBL - 2) ? i0 : (TBL - 2);
            float fr = x - (float)i0;
            float t0 = sh[i0], t1 = sh[i0 + 1];
            acc += fmaf(fr, t1 - t0, t0);
        }
#pragma unroll
        for (int off = 32; off > 0; off >>= 1) acc += __shfl_down(acc, off, 64);
        if (lane == 0) {
            // alpha_{0,n}: distance from node 0 to this row's node
            float dx = shx[0] - cx, dy = shy[0] - cy, dz = shz[0] - cz;
            float dd = fmaf(dx, dx, fmaf(dy, dy, dz * dz)) + 1e-12f;
            float x  = sqrtf(dd) * inv_h;
            int  i0  = (int)x;
            i0 = (i0 < TBL - 2) ? i0 : (TBL - 2);
            float fr = x - (float)i0;
            float al = fmaf(fr, sh[i0 + 1] - sh[i0], sh[i0]) - g0;
            p1 += al;
            p2 += al * acc;               // acc = S[b,n]
            if (n == 0) s0sh = acc;       // only block blk8==0, wave 0, r==0
        }
    }
    if (lane == 0) { wp1[wave] = p1; wp2[wave] = p2; }
    __syncthreads();
    if (tid == 0) {
        float P1 = 0.0f, P2 = 0.0f;
#pragma unroll
        for (int w = 0; w < 16; ++w) { P1 += wp1[w]; P2 += wp2[w]; }
        ws[blockIdx.x * 2 + 0] = P1;
        ws[blockIdx.x * 2 + 1] = P2;
        if (blk8 == 0) ws[WS_S0_OFF + b] = s0sh;
    }
}

// K2: 1 block x 64 thr. Sum 8 partials per batch, project.
__global__ __launch_bounds__(64) void finalize(const float* __restrict__ We,
                                               const float* __restrict__ be,
                                               const float* __restrict__ wa,
                                               const float* __restrict__ atom_emb,
                                               const float* __restrict__ Wq,
                                               const float* __restrict__ bq,
                                               const float* __restrict__ ws,
                                               float* __restrict__ out) {
    const float g0 = eval_g(0.0f, We, be, wa);   // exact, matches sh[0] in K1
    const int b = threadIdx.x;
    if (b < BB) {
        const float a = atom_emb[0];
        const float invN = 1.0f / (float)NN;
        float P1 = 0.0f, P2 = 0.0f;
#pragma unroll
        for (int j = 0; j < 8; ++j) {
            P1 += ws[(b * 8 + j) * 2 + 0];
            P2 += ws[(b * 8 + j) * 2 + 1];
        }
        float S0 = ws[WS_S0_OFF + b];
        float v1_0 = a * (1.0f + S0 * invN - g0);
        float corr = a * fmaf(P2, invN, (1.0f - g0) * P1);
        out[b] = fmaf(v1_0 + corr * invN, Wq[0], bq[0]);
    }
}

extern "C" void kernel_launch(void* const* d_in, const int* in_sizes, int n_in,
                              void* d_out, int out_size, void* d_ws, size_t ws_size,
                              hipStream_t stream) {
    const float* coords   = (const float*)d_in[0];  // (8,512,3)
    const float* atom_emb = (const float*)d_in[1];  // (1,1,1)
    const float* W_e      = (const float*)d_in[2];  // (20,16)
    const float* b_e      = (const float*)d_in[3];  // (16,)
    const float* w_a      = (const float*)d_in[4];  // (16,)
    const float* Wq       = (const float*)d_in[5];  // (1,1)
    const float* bq       = (const float*)d_in[6];  // (1,)
    float* out = (float*)d_out;                     // (8,1)
    float* ws  = (float*)d_ws;

    rows_partial<<<64, 1024, 0, stream>>>(coords, W_e, b_e, w_a, ws);
    finalize<<<1, 64, 0, stream>>>(W_e, b_e, w_a, atom_emb, Wq, bq, ws, out);
}

// Round 5
// 82.883 us; speedup vs baseline: 1.8868x; 1.6861x over previous
//
#include <hip/hip_runtime.h>
#include <math.h>

// GeometricAttentionClassifier: B=8, N=512, F=16, D=20, Fv=1.
// alpha depends only on pairwise distance d -> scalar g(d), tabulated ONCE:
//   g(d) = sum_f w_a[f]*tanh(sum_k exp(-10(d-0.1k)^2) W_e[k,f] + b_e[f]); g0=g(0)
// Order-2 stream collapses (a = atom_emb scalar):
//   S[b,m] = sum_k g(d_{mk});  v1[b,m] = a(1 + S[b,m]/N - g0)
//   out[b] = (v1[b,0] + (a/N)((1-g0)P1 + P2/N)) * Wq + bq
//   P1 = sum_m alpha_{0m},  P2 = sum_m alpha_{0m} S[b,m]
// R3 lesson: per-block LUT build = 64x redundant eval_g -> 59us.
// R4 BUG: block 1024->256 threads but coord staging stayed single-shot
//   (`tid<384` with 256 threads staged only 2/3 of coords; sc[1024..1536)
//   was uninitialized LDS -> absmax 0.64). R5: two-shot staging; K0 back to
//   precise tanhf (2048 evals total, off critical path; R3 was bf16-exact).

#define BB 8
#define NN 512
#define FF 16
#define DD 20
#define TBL 2048
#define DMAX 1.7320509f  // sqrt(3): coords uniform in [0,1)

// ws float layout: [0..TBL) LUT; [TBL .. TBL+512) per-block (P1,P2); [TBL+512+b] S0
#define WS_PART_OFF TBL
#define WS_S0_OFF (TBL + 512)

__device__ __forceinline__ float eval_g(float d, const float* __restrict__ We,
                                        const float* __restrict__ be,
                                        const float* __restrict__ wa) {
    float z[FF];
#pragma unroll
    for (int f = 0; f < FF; ++f) z[f] = be[f];
#pragma unroll
    for (int k = 0; k < DD; ++k) {
        float u = d - 0.1f * (float)k;
        float r = __expf(-10.0f * u * u);
#pragma unroll
        for (int f = 0; f < FF; ++f) z[f] = fmaf(r, We[k * FF + f], z[f]);
    }
    float g = 0.0f;
#pragma unroll
    for (int f = 0; f < FF; ++f) g += wa[f] * tanhf(z[f]);
    return g;
}

// K0: LUT to global ws, one eval per thread (2048 total — the only eval_g site).
__global__ __launch_bounds__(256) void build_table(const float* __restrict__ We,
                                                   const float* __restrict__ be,
                                                   const float* __restrict__ wa,
                                                   float* __restrict__ ws) {
    int i = blockIdx.x * blockDim.x + threadIdx.x;  // 0..2047
    float d = (DMAX / (float)(TBL - 1)) * (float)i;
    ws[i] = eval_g(d, We, be, wa);
}

// K1: 256 blocks x 256 thr. Block j: batch b=j>>5, rows [(j&31)*16, +16).
// Stage LUT (8KB, 512 float4) + coords (6KB, 384 float4) — both multi-shot
// for 256 threads. Pair loop; block-local partials; zero atomics.
__global__ __launch_bounds__(256) void rows_partial(const float* __restrict__ coords,
                                                    float* __restrict__ ws) {
    __shared__ float sh[TBL];       // LUT
    __shared__ float sc[NN * 3];    // coords, flat (stride-3 read = 2-way, free)
    __shared__ float wp[4][2];

    const int tid   = threadIdx.x;
    const int b     = blockIdx.x >> 5;
    const int chunk = blockIdx.x & 31;

    {   // stage LUT: 512 float4 over 256 threads (two shots)
        const float4* lut4 = (const float4*)ws;
        float4* sh4 = (float4*)sh;
        sh4[tid]       = lut4[tid];
        sh4[tid + 256] = lut4[tid + 256];
        // stage coords: 384 float4 over 256 threads (two shots; R4 bug fixed)
        const float4* cb4 = (const float4*)(coords + (size_t)b * NN * 3);
        float4* sc4 = (float4*)sc;
        sc4[tid] = cb4[tid];
        if (tid < 128) sc4[tid + 256] = cb4[tid + 256];
    }
    __syncthreads();

    const int wave = tid >> 6;
    const int lane = tid & 63;
    const float inv_h = (float)(TBL - 1) / DMAX;
    const float g0 = sh[0];

    float p1 = 0.0f, p2 = 0.0f;
#pragma unroll
    for (int r = 0; r < 4; ++r) {
        const int n = chunk * 16 + wave * 4 + r;
        const float cx = sc[3 * n], cy = sc[3 * n + 1], cz = sc[3 * n + 2];
        float acc = 0.0f;
#pragma unroll
        for (int it = 0; it < 8; ++it) {
            const int m = lane + it * 64;
            float dx = cx - sc[3 * m];
            float dy = cy - sc[3 * m + 1];
            float dz = cz - sc[3 * m + 2];
            float dd = fmaf(dx, dx, fmaf(dy, dy, dz * dz)) + 1e-12f;
            float x  = sqrtf(dd) * inv_h;
            int  i0  = (int)x;
            i0 = (i0 < TBL - 2) ? i0 : (TBL - 2);
            float fr = x - (float)i0;
            float t0 = sh[i0], t1 = sh[i0 + 1];
            acc += fmaf(fr, t1 - t0, t0);
        }
#pragma unroll
        for (int off = 32; off > 0; off >>= 1) acc += __shfl_down(acc, off, 64);
        if (lane == 0) {
            // alpha_{0,n} via LUT
            float dx = sc[0] - cx, dy = sc[1] - cy, dz = sc[2] - cz;
            float dd = fmaf(dx, dx, fmaf(dy, dy, dz * dz)) + 1e-12f;
            float x  = sqrtf(dd) * inv_h;
            int  i0  = (int)x;
            i0 = (i0 < TBL - 2) ? i0 : (TBL - 2);
            float fr = x - (float)i0;
            float al = fmaf(fr, sh[i0 + 1] - sh[i0], sh[i0]) - g0;
            p1 += al;
            p2 += al * acc;                       // acc = S[b,n]
            if (chunk == 0 && n == 0) ws[WS_S0_OFF + b] = acc;
        }
    }
    if (lane == 0) { wp[wave][0] = p1; wp[wave][1] = p2; }
    __syncthreads();
    if (tid == 0) {
        float P1 = wp[0][0] + wp[1][0] + wp[2][0] + wp[3][0];
        float P2 = wp[0][1] + wp[1][1] + wp[2][1] + wp[3][1];
        ws[WS_PART_OFF + blockIdx.x * 2 + 0] = P1;
        ws[WS_PART_OFF + blockIdx.x * 2 + 1] = P2;
    }
}

// K2: 1 block x 64 thr. Sum 32 chunk partials per batch, project.
__global__ __launch_bounds__(64) void finalize(const float* __restrict__ atom_emb,
                                               const float* __restrict__ Wq,
                                               const float* __restrict__ bq,
                                               const float* __restrict__ ws,
                                               float* __restrict__ out) {
    const int b = threadIdx.x;
    if (b < BB) {
        const float g0 = ws[0];                  // LUT[0] = g(0)
        const float a  = atom_emb[0];
        const float invN = 1.0f / (float)NN;
        float P1 = 0.0f, P2 = 0.0f;
        for (int j = 0; j < 32; ++j) {
            P1 += ws[WS_PART_OFF + (b * 32 + j) * 2 + 0];
            P2 += ws[WS_PART_OFF + (b * 32 + j) * 2 + 1];
        }
        float S0 = ws[WS_S0_OFF + b];
        float v1_0 = a * (1.0f + S0 * invN - g0);
        float corr = a * fmaf(P2, invN, (1.0f - g0) * P1);
        out[b] = fmaf(v1_0 + corr * invN, Wq[0], bq[0]);
    }
}

extern "C" void kernel_launch(void* const* d_in, const int* in_sizes, int n_in,
                              void* d_out, int out_size, void* d_ws, size_t ws_size,
                              hipStream_t stream) {
    const float* coords   = (const float*)d_in[0];  // (8,512,3)
    const float* atom_emb = (const float*)d_in[1];  // (1,1,1)
    const float* W_e      = (const float*)d_in[2];  // (20,16)
    const float* b_e      = (const float*)d_in[3];  // (16,)
    const float* w_a      = (const float*)d_in[4];  // (16,)
    const float* Wq       = (const float*)d_in[5];  // (1,1)
    const float* bq       = (const float*)d_in[6];  // (1,)
    float* out = (float*)d_out;                     // (8,1)
    float* ws  = (float*)d_ws;

    build_table<<<TBL / 256, 256, 0, stream>>>(W_e, b_e, w_a, ws);
    rows_partial<<<256, 256, 0, stream>>>(coords, ws);
    finalize<<<1, 64, 0, stream>>>(atom_emb, Wq, bq, ws, out);
}

// Round 6
// 76.914 us; speedup vs baseline: 2.0332x; 1.0776x over previous
//
#include <hip/hip_runtime.h>
#include <math.h>

// GeometricAttentionClassifier: B=8, N=512, F=16, D=20, Fv=1.
// alpha depends only on pairwise distance d -> scalar g(d):
//   g(d) = sum_f w_a[f]*tanh(sum_k exp(-10(d-0.1k)^2) W_e[k,f] + b_e[f]); g0=g(0)
// Order-2 stream collapses (a = atom_emb scalar):
//   S[b,m] = sum_k g(d_{mk});  v1[b,m] = a(1 + S[b,m]/N - g0)
//   out[b] = (v1[b,0] + (a/N)((1-g0)P1 + P2/N)) * Wq + bq
//   P1 = sum_m alpha_{0m},  P2 = sum_m alpha_{0m} S[b,m]
// Round history: R2 last-block ticket = 1024 serial cross-XCD atomics (+83us).
// R3 per-block 2048-entry precise-tanhf LUT = 64x redundant evals (59us).
// R5 (3 dispatches, global LUT): 82.9us total, all top-5 dispatches are the
// harness's two 256MiB 0xAA poison fills (~40us each @ ~85% HBM peak) = ~80us
// floor we cannot touch. R6: 3->2 dispatches — LUT shrunk to 512 entries and
// built in-LDS per block with rcp-based fast tanh (2 evals/thread, ~0.8us,
// parallel across 256 blocks). Lerp err ~5e-5 << 4.06e-2 threshold.

#define BB 8
#define NN 512
#define FF 16
#define DD 20
#define TBL 512
#define DMAX 1.7320509f  // sqrt(3): coords uniform in [0,1)

// ws float layout: [0..512) per-block (P1,P2) pairs; [512+b] = S0 per batch
#define WS_PART_OFF 0
#define WS_S0_OFF 512

__device__ __forceinline__ float fast_tanh(float x) {
    // tanh(x) = 1 - 2/(e^{2x}+1); exp->inf => rcp->0 saturates to +1, e->0 => -1.
    float e = __expf(2.0f * x);
    return 1.0f - 2.0f * __builtin_amdgcn_rcpf(e + 1.0f);
}

__device__ __forceinline__ float eval_g(float d, const float* __restrict__ We,
                                        const float* __restrict__ be,
                                        const float* __restrict__ wa) {
    float z[FF];
#pragma unroll
    for (int f = 0; f < FF; ++f) z[f] = be[f];
#pragma unroll
    for (int k = 0; k < DD; ++k) {
        float u = d - 0.1f * (float)k;
        float r = __expf(-10.0f * u * u);
#pragma unroll
        for (int f = 0; f < FF; ++f) z[f] = fmaf(r, We[k * FF + f], z[f]);
    }
    float g = 0.0f;
#pragma unroll
    for (int f = 0; f < FF; ++f) g += wa[f] * fast_tanh(z[f]);
    return g;
}

// K1: 256 blocks x 256 thr. Block j: batch b=j>>5, rows [(j&31)*16, +16).
// Per-block: build 512-entry LUT in-LDS (2 evals/thread), stage coords (two-shot
// float4 — R4's bug was single-shot), pair loop, block-local P1/P2. No atomics.
__global__ __launch_bounds__(256) void rows_partial(const float* __restrict__ coords,
                                                    const float* __restrict__ We,
                                                    const float* __restrict__ be,
                                                    const float* __restrict__ wa,
                                                    float* __restrict__ ws) {
    __shared__ float sh[TBL];       // LUT (2 KB)
    __shared__ float sc[NN * 3];    // coords flat (6 KB)
    __shared__ float wp[4][2];

    const int tid   = threadIdx.x;
    const int b     = blockIdx.x >> 5;
    const int chunk = blockIdx.x & 31;

    {   // stage coords: 384 float4 over 256 threads (two shots)
        const float4* cb4 = (const float4*)(coords + (size_t)b * NN * 3);
        float4* sc4 = (float4*)sc;
        sc4[tid] = cb4[tid];
        if (tid < 128) sc4[tid + 256] = cb4[tid + 256];
        // build LUT in-LDS: entries tid and tid+256 (overlaps with loads in flight)
        const float h = DMAX / (float)(TBL - 1);
        sh[tid]       = eval_g(h * (float)tid, We, be, wa);
        sh[tid + 256] = eval_g(h * (float)(tid + 256), We, be, wa);
    }
    __syncthreads();

    const int wave = tid >> 6;
    const int lane = tid & 63;
    const float inv_h = (float)(TBL - 1) / DMAX;
    const float g0 = sh[0];

    float p1 = 0.0f, p2 = 0.0f;
#pragma unroll
    for (int r = 0; r < 4; ++r) {
        const int n = chunk * 16 + wave * 4 + r;
        const float cx = sc[3 * n], cy = sc[3 * n + 1], cz = sc[3 * n + 2];
        float acc = 0.0f;
#pragma unroll
        for (int it = 0; it < 8; ++it) {
            const int m = lane + it * 64;
            float dx = cx - sc[3 * m];
            float dy = cy - sc[3 * m + 1];
            float dz = cz - sc[3 * m + 2];
            float dd = fmaf(dx, dx, fmaf(dy, dy, dz * dz)) + 1e-12f;
            float x  = sqrtf(dd) * inv_h;
            int  i0  = (int)x;
            i0 = (i0 < TBL - 2) ? i0 : (TBL - 2);
            float fr = x - (float)i0;
            float t0 = sh[i0], t1 = sh[i0 + 1];
            acc += fmaf(fr, t1 - t0, t0);
        }
#pragma unroll
        for (int off = 32; off > 0; off >>= 1) acc += __shfl_down(acc, off, 64);
        if (lane == 0) {
            // alpha_{0,n} via LUT
            float dx = sc[0] - cx, dy = sc[1] - cy, dz = sc[2] - cz;
            float dd = fmaf(dx, dx, fmaf(dy, dy, dz * dz)) + 1e-12f;
            float x  = sqrtf(dd) * inv_h;
            int  i0  = (int)x;
            i0 = (i0 < TBL - 2) ? i0 : (TBL - 2);
            float fr = x - (float)i0;
            float al = fmaf(fr, sh[i0 + 1] - sh[i0], sh[i0]) - g0;
            p1 += al;
            p2 += al * acc;                       // acc = S[b,n]
            if (chunk == 0 && n == 0) ws[WS_S0_OFF + b] = acc;
        }
    }
    if (lane == 0) { wp[wave][0] = p1; wp[wave][1] = p2; }
    __syncthreads();
    if (tid == 0) {
        float P1 = wp[0][0] + wp[1][0] + wp[2][0] + wp[3][0];
        float P2 = wp[0][1] + wp[1][1] + wp[2][1] + wp[3][1];
        ws[WS_PART_OFF + blockIdx.x * 2 + 0] = P1;
        ws[WS_PART_OFF + blockIdx.x * 2 + 1] = P2;
    }
}

// K2: 1 block x 64 thr. Sum 32 chunk partials per batch, project.
// g0 recomputed via the identical eval_g code path (matches K1's sh[0]).
__global__ __launch_bounds__(64) void finalize(const float* __restrict__ We,
                                               const float* __restrict__ be,
                                               const float* __restrict__ wa,
                                               const float* __restrict__ atom_emb,
                                               const float* __restrict__ Wq,
                                               const float* __restrict__ bq,
                                               const float* __restrict__ ws,
                                               float* __restrict__ out) {
    const int b = threadIdx.x;
    if (b < BB) {
        const float g0 = eval_g(0.0f, We, be, wa);
        const float a  = atom_emb[0];
        const float invN = 1.0f / (float)NN;
        float P1 = 0.0f, P2 = 0.0f;
        for (int j = 0; j < 32; ++j) {
            P1 += ws[WS_PART_OFF + (b * 32 + j) * 2 + 0];
            P2 += ws[WS_PART_OFF + (b * 32 + j) * 2 + 1];
        }
        float S0 = ws[WS_S0_OFF + b];
        float v1_0 = a * (1.0f + S0 * invN - g0);
        float corr = a * fmaf(P2, invN, (1.0f - g0) * P1);
        out[b] = fmaf(v1_0 + corr * invN, Wq[0], bq[0]);
    }
}

extern "C" void kernel_launch(void* const* d_in, const int* in_sizes, int n_in,
                              void* d_out, int out_size, void* d_ws, size_t ws_size,
                              hipStream_t stream) {
    const float* coords   = (const float*)d_in[0];  // (8,512,3)
    const float* atom_emb = (const float*)d_in[1];  // (1,1,1)
    const float* W_e      = (const float*)d_in[2];  // (20,16)
    const float* b_e      = (const float*)d_in[3];  // (16,)
    const float* w_a      = (const float*)d_in[4];  // (16,)
    const float* Wq       = (const float*)d_in[5];  // (1,1)
    const float* bq       = (const float*)d_in[6];  // (1,)
    float* out = (float*)d_out;                     // (8,1)
    float* ws  = (float*)d_ws;

    rows_partial<<<256, 256, 0, stream>>>(coords, W_e, b_e, w_a, ws);
    finalize<<<1, 64, 0, stream>>>(W_e, b_e, w_a, atom_emb, Wq, bq, ws, out);
}